// Round 1
// baseline (1643.344 us; speedup 1.0000x reference)
//
#include <hip/hip_runtime.h>

typedef _Float16 h16;
typedef __attribute__((ext_vector_type(4))) _Float16 h16x4;
typedef __attribute__((ext_vector_type(8))) _Float16 h16x8;
typedef __attribute__((ext_vector_type(4))) float f32x4;

#define SCALE 0.17677669529663687f

// workspace layout (bytes)
#define O_BYTES 205520896ULL              // 200704*512*2 (pre-proj output, fp16)
#define W1_OFF  (O_BYTES)                 // qkv_w fp16: 512*1536*2 = 1572864
#define W2_OFF  (W1_OFF + 1572864ULL)     // proj_w fp16: 512*512*2 = 524288
#define BT_OFF  (W2_OFF + 524288ULL)      // biasT f32: 16*64*64*4 = 262144

// ---------------- weight conversion fp32 -> fp16 ----------------
__global__ __launch_bounds__(256) void wa_convert_w(
    const float* __restrict__ qkv_w, const float* __restrict__ proj_w,
    h16* __restrict__ w1, h16* __restrict__ w2) {
  int i = blockIdx.x * 256 + threadIdx.x;   // 262144 threads, 4 elems each
  int base = i * 4;
  const float* src; h16* dst; int off;
  if (base < 786432) { src = qkv_w; dst = w1; off = base; }
  else               { src = proj_w; dst = w2; off = base - 786432; }
  float4 v = *(const float4*)(src + off);
  h16x4 h = { (h16)v.x, (h16)v.y, (h16)v.z, (h16)v.w };
  *(h16x4*)(dst + off) = h;
}

// ---------------- relative-position bias, transposed + masked ----------------
// biasT[h][j][q] = bias_table[rel(q,j)][h]  (j = key, q = query), -1e30 where padded
__global__ __launch_bounds__(256) void wa_build_bias(
    const float* __restrict__ table, float* __restrict__ biasT) {
  int idx = blockIdx.x * 256 + threadIdx.x;  // 65536
  int h = idx >> 12, j = (idx >> 6) & 63, q = idx & 63;
  float v = -1e30f;
  if (j < 49 && q < 49) {
    int rel = (q / 7 - j / 7 + 6) * 13 + (q % 7 - j % 7 + 6);
    v = table[rel * 16 + h];
  }
  biasT[idx] = v;
}

// ---------------- fused QKV projection + window attention ----------------
// grid: 4096 windows * 4 head-groups; block: 256 thr = 4 waves; wave = one head.
__global__ __launch_bounds__(256) void wa_qkv_attn(
    const float* __restrict__ x, const float* __restrict__ qkv_b,
    const h16* __restrict__ w1, const float* __restrict__ biasT,
    h16* __restrict__ O) {
  __shared__ __align__(16) char ldsbuf[55296];
  const int tid = threadIdx.x;
  const int wave = tid >> 6, lane = tid & 63;
  const int l15 = lane & 15, lg = lane >> 4;
  const int w = blockIdx.x >> 2, g = blockIdx.x & 3;
  const int head = g * 4 + wave;
  const int rowbase = w * 49;

  h16* Alds = (h16*)ldsbuf;                 // [49][36] staged x tile (fp16)
  h16* Blds = (h16*)(ldsbuf + 3584);        // [32][400] staged qkv_w slice
  h16* Qw = (h16*)(ldsbuf + wave * 13824);  // per-wave [64][36]; overlays staging (phase-disjoint)
  h16* Kw = Qw + 64 * 36;
  h16* Vw = Kw + 64 * 36;

  f32x4 acc[4][6];
  #pragma unroll
  for (int a = 0; a < 4; ++a)
    #pragma unroll
    for (int b = 0; b < 6; ++b) acc[a][b] = (f32x4){0.f, 0.f, 0.f, 0.f};

  // ---- GEMM phase: [64(pad49) x 512] @ [512 x 96-per-wave] ----
  for (int kt = 0; kt < 16; ++kt) {       // BK = 32
    #pragma unroll
    for (int p = 0; p < 2; ++p) {         // stage A: 49x32 fp32 -> fp16
      int idx = tid + p * 256;
      if (idx < 392) {
        int r = idx >> 3, c4 = (idx & 7) << 2;
        float4 v = *(const float4*)(x + (size_t)(rowbase + r) * 512 + kt * 32 + c4);
        h16x4 hv = { (h16)v.x, (h16)v.y, (h16)v.z, (h16)v.w };
        *(h16x4*)(Alds + r * 36 + c4) = hv;
      }
    }
    #pragma unroll
    for (int p = 0; p < 6; ++p) {         // stage B: 32 x (3 strips of 128)
      int idx = tid + p * 256;
      int r = idx / 48, c = idx - r * 48;
      int strip = c >> 4, off = (c & 15) << 3;
      h16x8 v = *(const h16x8*)(w1 + (size_t)(kt * 32 + r) * 1536 + strip * 512 + g * 128 + off);
      *(h16x8*)(Blds + r * 400 + strip * 128 + off) = v;
    }
    __syncthreads();
    #pragma unroll
    for (int ks = 0; ks < 2; ++ks) {
      h16x4 af[4], bf[6];
      #pragma unroll
      for (int mt = 0; mt < 4; ++mt) {
        int row = 16 * mt + l15; if (row > 48) row = 48;  // clamp pad rows
        af[mt] = *(const h16x4*)(Alds + row * 36 + ks * 16 + lg * 4);
      }
      #pragma unroll
      for (int nt = 0; nt < 6; ++nt) {
        int col = (nt >> 1) * 128 + wave * 32 + ((nt & 1) << 4) + l15;
        int kb = (ks * 16 + lg * 4) * 400 + col;
        bf[nt] = (h16x4){ Blds[kb], Blds[kb + 400], Blds[kb + 800], Blds[kb + 1200] };
      }
      #pragma unroll
      for (int mt = 0; mt < 4; ++mt)
        #pragma unroll
        for (int nt = 0; nt < 6; ++nt)
          acc[mt][nt] = __builtin_amdgcn_mfma_f32_16x16x16f16(af[mt], bf[nt], acc[mt][nt], 0, 0, 0);
    }
    __syncthreads();
  }

  // ---- epilogue: +qkv_b, scale Q, write Q/K/V fp16 into per-wave LDS ----
  #pragma unroll
  for (int nt = 0; nt < 6; ++nt) {
    int s = nt >> 1;                       // 0=Q 1=K 2=V
    int dcol = ((nt & 1) << 4) + l15;      // 0..31 within head
    float bb = qkv_b[s * 512 + head * 32 + dcol];
    h16* dst = (s == 0) ? Qw : (s == 1) ? Kw : Vw;
    float sc = (s == 0) ? SCALE : 1.0f;
    #pragma unroll
    for (int mt = 0; mt < 4; ++mt)
      #pragma unroll
      for (int r = 0; r < 4; ++r) {
        int row = 16 * mt + 4 * lg + r;
        dst[row * 36 + dcol] = (h16)((acc[mt][nt][r] + bb) * sc);
      }
  }

  // ---- attention (per-wave, private LDS; no cross-wave sync needed) ----
  // S^T = K * Q^T  -> C frag: (j = 16mt+4lg+r, q = 16nt+l15)
  f32x4 st[4][4];
  #pragma unroll
  for (int a = 0; a < 4; ++a)
    #pragma unroll
    for (int b = 0; b < 4; ++b) st[a][b] = (f32x4){0.f, 0.f, 0.f, 0.f};
  #pragma unroll
  for (int ds2 = 0; ds2 < 2; ++ds2) {
    h16x4 kf[4], qf[4];
    #pragma unroll
    for (int t = 0; t < 4; ++t) {
      kf[t] = *(const h16x4*)(Kw + (16 * t + l15) * 36 + ds2 * 16 + lg * 4);
      qf[t] = *(const h16x4*)(Qw + (16 * t + l15) * 36 + ds2 * 16 + lg * 4);
    }
    #pragma unroll
    for (int mt = 0; mt < 4; ++mt)
      #pragma unroll
      for (int nt = 0; nt < 4; ++nt)
        st[mt][nt] = __builtin_amdgcn_mfma_f32_16x16x16f16(kf[mt], qf[nt], st[mt][nt], 0, 0, 0);
  }

  // bias + in-register softmax (reduce over 4 regs x 4 mtiles local, then lanes ^16,^32)
  const float* bT = biasT + head * 4096;
  float rinv[4];
  #pragma unroll
  for (int nt = 0; nt < 4; ++nt) {
    float mx = -3.4e38f;
    #pragma unroll
    for (int mt = 0; mt < 4; ++mt)
      #pragma unroll
      for (int r = 0; r < 4; ++r) {
        float v = st[mt][nt][r] + bT[(16 * mt + 4 * lg + r) * 64 + 16 * nt + l15];
        st[mt][nt][r] = v;
        mx = fmaxf(mx, v);
      }
    mx = fmaxf(mx, __shfl_xor(mx, 16, 64));
    mx = fmaxf(mx, __shfl_xor(mx, 32, 64));
    float sum = 0.f;
    #pragma unroll
    for (int mt = 0; mt < 4; ++mt)
      #pragma unroll
      for (int r = 0; r < 4; ++r) {
        float p = __expf(st[mt][nt][r] - mx);
        st[mt][nt][r] = p;
        sum += p;
      }
    sum += __shfl_xor(sum, 16, 64);
    sum += __shfl_xor(sum, 32, 64);
    rinv[nt] = 1.0f / sum;
  }

  // P^T frags are already in B-operand layout for O^T = V^T * P^T
  h16x4 pf[4][4];
  #pragma unroll
  for (int kt = 0; kt < 4; ++kt)
    #pragma unroll
    for (int nt = 0; nt < 4; ++nt)
      pf[kt][nt] = (h16x4){ (h16)st[kt][nt][0], (h16)st[kt][nt][1],
                            (h16)st[kt][nt][2], (h16)st[kt][nt][3] };

  f32x4 ot[2][4];
  #pragma unroll
  for (int a = 0; a < 2; ++a)
    #pragma unroll
    for (int b = 0; b < 4; ++b) ot[a][b] = (f32x4){0.f, 0.f, 0.f, 0.f};
  #pragma unroll
  for (int dm = 0; dm < 2; ++dm) {
    #pragma unroll
    for (int kt = 0; kt < 4; ++kt) {
      int jb = 16 * kt + 4 * lg;
      int d = 16 * dm + l15;
      h16x4 vf = (h16x4){ Vw[(jb + 0) * 36 + d], Vw[(jb + 1) * 36 + d],
                          Vw[(jb + 2) * 36 + d], Vw[(jb + 3) * 36 + d] };
      #pragma unroll
      for (int nt = 0; nt < 4; ++nt)
        ot[dm][nt] = __builtin_amdgcn_mfma_f32_16x16x16f16(vf, pf[kt][nt], ot[dm][nt], 0, 0, 0);
    }
  }

  // normalize, repack O^T -> row-major [64][36] in Qw (now free), then coalesced copy-out
  #pragma unroll
  for (int nt = 0; nt < 4; ++nt)
    #pragma unroll
    for (int dm = 0; dm < 2; ++dm) {
      h16x4 ov;
      #pragma unroll
      for (int r = 0; r < 4; ++r) ov[r] = (h16)(ot[dm][nt][r] * rinv[nt]);
      int q = 16 * nt + l15;
      *(h16x4*)(Qw + q * 36 + 16 * dm + 4 * lg) = ov;
    }
  if (lane < 49) {
    h16* gdst = O + (size_t)(rowbase + lane) * 512 + head * 32;
    #pragma unroll
    for (int c = 0; c < 4; ++c) {
      h16x4 v0 = *(const h16x4*)(Qw + lane * 36 + c * 8);
      h16x4 v1 = *(const h16x4*)(Qw + lane * 36 + c * 8 + 4);
      *(h16x4*)(gdst + c * 8) = v0;
      *(h16x4*)(gdst + c * 8 + 4) = v1;
    }
  }
}

// ---------------- output projection: out = O @ proj_w + proj_b ----------------
// grid: 1568 row-tiles * 4 col-tiles; 128x128 tile, 4 waves of 64x64
__global__ __launch_bounds__(256) void wa_proj(
    const h16* __restrict__ O, const h16* __restrict__ w2,
    const float* __restrict__ proj_b, float* __restrict__ out) {
  __shared__ __align__(16) h16 Alds[128][40];
  __shared__ __align__(16) h16 Blds[32][144];
  const int tid = threadIdx.x;
  const int wave = tid >> 6, lane = tid & 63;
  const int l15 = lane & 15, lg = lane >> 4;
  const int rowt = blockIdx.x >> 2, colt = blockIdx.x & 3;
  const int wr = wave >> 1, wc = wave & 1;

  f32x4 acc[4][4];
  #pragma unroll
  for (int a = 0; a < 4; ++a)
    #pragma unroll
    for (int b = 0; b < 4; ++b) acc[a][b] = (f32x4){0.f, 0.f, 0.f, 0.f};

  for (int kt = 0; kt < 16; ++kt) {
    #pragma unroll
    for (int p = 0; p < 2; ++p) {         // stage A 128x32
      int idx = tid + p * 256;
      int r = idx >> 2, c8 = (idx & 3) << 3;
      h16x8 v = *(const h16x8*)(O + (size_t)(rowt * 128 + r) * 512 + kt * 32 + c8);
      *(h16x8*)(&Alds[r][c8]) = v;
    }
    #pragma unroll
    for (int p = 0; p < 2; ++p) {         // stage B 32x128
      int idx = tid + p * 256;
      int r = idx >> 4, c8 = (idx & 15) << 3;
      h16x8 v = *(const h16x8*)(w2 + (size_t)(kt * 32 + r) * 512 + colt * 128 + c8);
      *(h16x8*)(&Blds[r][c8]) = v;
    }
    __syncthreads();
    #pragma unroll
    for (int ks = 0; ks < 2; ++ks) {
      h16x4 af[4], bf[4];
      #pragma unroll
      for (int mt = 0; mt < 4; ++mt)
        af[mt] = *(const h16x4*)(&Alds[wr * 64 + mt * 16 + l15][ks * 16 + lg * 4]);
      #pragma unroll
      for (int nt = 0; nt < 4; ++nt) {
        int col = wc * 64 + nt * 16 + l15;
        int kb = ks * 16 + lg * 4;
        bf[nt] = (h16x4){ Blds[kb][col], Blds[kb + 1][col], Blds[kb + 2][col], Blds[kb + 3][col] };
      }
      #pragma unroll
      for (int mt = 0; mt < 4; ++mt)
        #pragma unroll
        for (int nt = 0; nt < 4; ++nt)
          acc[mt][nt] = __builtin_amdgcn_mfma_f32_16x16x16f16(af[mt], bf[nt], acc[mt][nt], 0, 0, 0);
    }
    __syncthreads();
  }
  #pragma unroll
  for (int nt = 0; nt < 4; ++nt) {
    int col = colt * 128 + wc * 64 + nt * 16 + l15;
    float pb = proj_b[col];
    #pragma unroll
    for (int mt = 0; mt < 4; ++mt) {
      int row = rowt * 128 + wr * 64 + mt * 16 + 4 * lg;
      #pragma unroll
      for (int r = 0; r < 4; ++r)
        out[(size_t)(row + r) * 512 + col] = acc[mt][nt][r] + pb;
    }
  }
}

extern "C" void kernel_launch(void* const* d_in, const int* in_sizes, int n_in,
                              void* d_out, int out_size, void* d_ws, size_t ws_size,
                              hipStream_t stream) {
  const float* x          = (const float*)d_in[0];
  const float* qkv_w      = (const float*)d_in[1];
  const float* qkv_b      = (const float*)d_in[2];
  const float* proj_w     = (const float*)d_in[3];
  const float* proj_b     = (const float*)d_in[4];
  const float* bias_table = (const float*)d_in[5];
  float* out = (float*)d_out;

  char* ws = (char*)d_ws;
  h16*   O     = (h16*)ws;
  h16*   w1    = (h16*)(ws + W1_OFF);
  h16*   w2    = (h16*)(ws + W2_OFF);
  float* biasT = (float*)(ws + BT_OFF);

  wa_convert_w<<<1024, 256, 0, stream>>>(qkv_w, proj_w, w1, w2);
  wa_build_bias<<<256, 256, 0, stream>>>(bias_table, biasT);
  wa_qkv_attn<<<4096 * 4, 256, 0, stream>>>(x, qkv_b, w1, biasT, O);
  wa_proj<<<1568 * 4, 256, 0, stream>>>(O, w2, proj_b, out);
}

// Round 2
// 1475.430 us; speedup vs baseline: 1.1138x; 1.1138x over previous
//
#include <hip/hip_runtime.h>

typedef _Float16 h16;
typedef __attribute__((ext_vector_type(4))) _Float16 h16x4;
typedef __attribute__((ext_vector_type(8))) _Float16 h16x8;
typedef __attribute__((ext_vector_type(4))) float f32x4;

#define SCALE 0.17677669529663687f

// workspace layout (bytes)
#define O_BYTES 205520896ULL              // 200704*512*2 (pre-proj output, fp16)
#define W1T_OFF (O_BYTES)                 // w1T fp16 [1536][512]: 1572864
#define W2_OFF  (W1T_OFF + 1572864ULL)    // proj_w fp16 [512][512]: 524288
#define BT_OFF  (W2_OFF + 524288ULL)      // biasT f32 [16][64 q][64 j]: 262144

// ---------------- x fp32 -> fp16 (written into d_out, dead until wa_proj) ----------------
__global__ __launch_bounds__(256) void wa_convert_x(
    const float* __restrict__ x, h16* __restrict__ x16) {
  size_t i = ((size_t)blockIdx.x * 256 + threadIdx.x) * 8;
  float4 a = *(const float4*)(x + i);
  float4 b = *(const float4*)(x + i + 4);
  h16x8 h = { (h16)a.x, (h16)a.y, (h16)a.z, (h16)a.w,
              (h16)b.x, (h16)b.y, (h16)b.z, (h16)b.w };
  *(h16x8*)(x16 + i) = h;
}

// ---------------- proj_w fp32 -> fp16 ----------------
__global__ __launch_bounds__(256) void wa_convert_pw(
    const float* __restrict__ proj_w, h16* __restrict__ w2) {
  int i = (blockIdx.x * 256 + threadIdx.x) * 4;
  float4 v = *(const float4*)(proj_w + i);
  h16x4 h = { (h16)v.x, (h16)v.y, (h16)v.z, (h16)v.w };
  *(h16x4*)(w2 + i) = h;
}

// ---------------- qkv_w [512c][1536o] fp32 -> w1T [1536o][512c] fp16 ----------------
__global__ __launch_bounds__(256) void wa_transpose_w1(
    const float* __restrict__ qkv_w, h16* __restrict__ w1T) {
  __shared__ h16 T[32][33];
  int tx = threadIdx.x & 31, ty = threadIdx.x >> 5;   // 32 x 8
  int bo = blockIdx.x % 48, bc = blockIdx.x / 48;     // 48 o-tiles, 16 c-tiles
  #pragma unroll
  for (int i = 0; i < 4; ++i) {
    int c = bc * 32 + ty + 8 * i, o = bo * 32 + tx;
    T[ty + 8 * i][tx] = (h16)qkv_w[c * 1536 + o];     // T[c_local][o_local]
  }
  __syncthreads();
  #pragma unroll
  for (int i = 0; i < 4; ++i) {
    int o_l = ty + 8 * i;
    w1T[(size_t)(bo * 32 + o_l) * 512 + bc * 32 + tx] = T[tx][o_l];
  }
}

// ---------------- relative-position bias: biasT[h][q][j], -1e30 where padded ----------------
__global__ __launch_bounds__(256) void wa_build_bias(
    const float* __restrict__ table, float* __restrict__ biasT) {
  int idx = blockIdx.x * 256 + threadIdx.x;  // 65536
  int h = idx >> 12, q = (idx >> 6) & 63, j = idx & 63;
  float v = -1e30f;
  if (j < 49 && q < 49) {
    int rel = (q / 7 - j / 7 + 6) * 13 + (q % 7 - j % 7 + 6);
    v = table[rel * 16 + h];
  }
  biasT[idx] = v;
}

// ---------------- fused QKV projection + window attention, fully register-resident ----------------
// grid: 4096 windows * 4 head-groups; block 256 = 4 waves; wave = one head.
// Trick: C-frag of a transposed GEMM == A-operand frag; C-frag == B-operand frag (row<->k).
//  accQ = Q^T (Wq^T @ x^T)  -> B-operand of S^T = K Q^T
//  accK = K^T (Wk^T @ x^T)  -> A-operand of S^T
//  accV = V   (x @ Wv)      -> A-operand of O^T = V^T P^T
//  S^T C-frags               -> B-operand (P^T) of O^T
__global__ __launch_bounds__(256, 3) void wa_qkv_attn(
    const h16* __restrict__ x16, const float* __restrict__ qkv_b,
    const h16* __restrict__ w1T, const float* __restrict__ biasT,
    h16* __restrict__ O) {
  __shared__ __align__(16) char ldsbuf[32256];
  h16* Xs = (h16*)ldsbuf;               // [64][36] fp16 x-tile (rows 49..63 zero)
  h16* Ws = (h16*)(ldsbuf + 4608);      // [384][36] fp16 w1T tile (Q|K|V x 4 heads x 32)
  const int tid = threadIdx.x;
  const int wave = tid >> 6, lane = tid & 63;
  const int l15 = lane & 15, lg = lane >> 4;
  const int w = blockIdx.x >> 2, g = blockIdx.x & 3;
  const int head = g * 4 + wave;
  const size_t rowbase = (size_t)w * 49;

  // zero the pad token rows (49..63, cols 0..31) once; stays valid all iterations
  if (tid < 120) {
    int r = 49 + (tid >> 3), c = (tid & 7) * 4;
    *(h16x4*)(Xs + r * 36 + c) = (h16x4){0, 0, 0, 0};
  }

  f32x4 accQ[2][4], accK[2][4], accV[4][2];
  #pragma unroll
  for (int d = 0; d < 2; ++d)
    #pragma unroll
    for (int t = 0; t < 4; ++t) {
      accQ[d][t] = (f32x4){0.f, 0.f, 0.f, 0.f};
      accK[d][t] = (f32x4){0.f, 0.f, 0.f, 0.f};
      accV[t][d] = (f32x4){0.f, 0.f, 0.f, 0.f};
    }

  for (int kt = 0; kt < 16; ++kt) {     // BK = 32
    if (tid < 196) {                    // stage x-tile 49 x 32
      int r = tid >> 2, c8 = (tid & 3) * 8;
      *(h16x8*)(Xs + r * 36 + c8) =
          *(const h16x8*)(x16 + (rowbase + r) * 512 + kt * 32 + c8);
    }
    #pragma unroll
    for (int p = 0; p < 6; ++p) {       // stage w1T tile 384 x 32
      int idx = tid + p * 256;
      int row = idx >> 2, c8 = (idx & 3) * 8;
      int s = row >> 7, rem = row & 127;
      int o = s * 512 + g * 128 + rem;
      *(h16x8*)(Ws + row * 36 + c8) =
          *(const h16x8*)(w1T + (size_t)o * 512 + kt * 32 + c8);
    }
    __syncthreads();
    #pragma unroll
    for (int ks = 0; ks < 2; ++ks) {
      const int ko = ks * 16 + lg * 4;
      h16x4 xf[4], wq[2], wk[2], wv[2];
      #pragma unroll
      for (int t = 0; t < 4; ++t)
        xf[t] = *(const h16x4*)(Xs + (16 * t + l15) * 36 + ko);
      #pragma unroll
      for (int d = 0; d < 2; ++d) {
        wq[d] = *(const h16x4*)(Ws + (      wave * 32 + 16 * d + l15) * 36 + ko);
        wk[d] = *(const h16x4*)(Ws + (128 + wave * 32 + 16 * d + l15) * 36 + ko);
        wv[d] = *(const h16x4*)(Ws + (256 + wave * 32 + 16 * d + l15) * 36 + ko);
      }
      #pragma unroll
      for (int d = 0; d < 2; ++d)
        #pragma unroll
        for (int t = 0; t < 4; ++t) {
          accQ[d][t] = __builtin_amdgcn_mfma_f32_16x16x16f16(wq[d], xf[t], accQ[d][t], 0, 0, 0);
          accK[d][t] = __builtin_amdgcn_mfma_f32_16x16x16f16(wk[d], xf[t], accK[d][t], 0, 0, 0);
          accV[t][d] = __builtin_amdgcn_mfma_f32_16x16x16f16(xf[t], wv[d], accV[t][d], 0, 0, 0);
        }
    }
    __syncthreads();
  }

  // ---- epilogue: bias (+scale Q), convert to fp16 operand frags, all in registers ----
  h16x4 Qh[2][4], Kh[2][4], Vh[4][2];
  #pragma unroll
  for (int d = 0; d < 2; ++d) {
    float bq[4], bk[4];
    #pragma unroll
    for (int r = 0; r < 4; ++r) {
      bq[r] = qkv_b[head * 32 + 16 * d + 4 * lg + r];
      bk[r] = qkv_b[512 + head * 32 + 16 * d + 4 * lg + r];
    }
    #pragma unroll
    for (int t = 0; t < 4; ++t)
      #pragma unroll
      for (int r = 0; r < 4; ++r) {
        Qh[d][t][r] = (h16)((accQ[d][t][r] + bq[r]) * SCALE);
        Kh[d][t][r] = (h16)(accK[d][t][r] + bk[r]);
      }
    float bv = qkv_b[1024 + head * 32 + 16 * d + l15];
    #pragma unroll
    for (int t = 0; t < 4; ++t)
      #pragma unroll
      for (int r = 0; r < 4; ++r)
        Vh[t][d][r] = (h16)(accV[t][d][r] + bv);
  }

  // ---- S^T = K Q^T (register operands) ----
  f32x4 st[4][4];
  #pragma unroll
  for (int a = 0; a < 4; ++a)
    #pragma unroll
    for (int b = 0; b < 4; ++b) st[a][b] = (f32x4){0.f, 0.f, 0.f, 0.f};
  #pragma unroll
  for (int d = 0; d < 2; ++d)
    #pragma unroll
    for (int jt = 0; jt < 4; ++jt)
      #pragma unroll
      for (int qt = 0; qt < 4; ++qt)
        st[jt][qt] = __builtin_amdgcn_mfma_f32_16x16x16f16(Kh[d][jt], Qh[d][qt], st[jt][qt], 0, 0, 0);

  // ---- bias + in-register softmax over j (regs x jt, then lanes ^16,^32) ----
  const float* bT = biasT + head * 4096;
  float rinv[4];
  #pragma unroll
  for (int qt = 0; qt < 4; ++qt) {
    int q = 16 * qt + l15;
    float mx = -3.4e38f;
    #pragma unroll
    for (int jt = 0; jt < 4; ++jt) {
      float4 bv = *(const float4*)(bT + q * 64 + 16 * jt + 4 * lg);
      #pragma unroll
      for (int r = 0; r < 4; ++r) {
        float v = st[jt][qt][r] + ((const float*)&bv)[r];
        st[jt][qt][r] = v;
        mx = fmaxf(mx, v);
      }
    }
    mx = fmaxf(mx, __shfl_xor(mx, 16, 64));
    mx = fmaxf(mx, __shfl_xor(mx, 32, 64));
    float sum = 0.f;
    #pragma unroll
    for (int jt = 0; jt < 4; ++jt)
      #pragma unroll
      for (int r = 0; r < 4; ++r) {
        float p = __expf(st[jt][qt][r] - mx);
        st[jt][qt][r] = p;
        sum += p;
      }
    sum += __shfl_xor(sum, 16, 64);
    sum += __shfl_xor(sum, 32, 64);
    rinv[qt] = 1.0f / sum;
  }

  // P^T frags already in B-operand layout
  h16x4 pf[4][4];
  #pragma unroll
  for (int jt = 0; jt < 4; ++jt)
    #pragma unroll
    for (int qt = 0; qt < 4; ++qt)
      pf[jt][qt] = (h16x4){ (h16)st[jt][qt][0], (h16)st[jt][qt][1],
                            (h16)st[jt][qt][2], (h16)st[jt][qt][3] };

  // ---- O^T = V^T P^T (register operands) ----
  f32x4 ot[2][4];
  #pragma unroll
  for (int d = 0; d < 2; ++d)
    #pragma unroll
    for (int qt = 0; qt < 4; ++qt) ot[d][qt] = (f32x4){0.f, 0.f, 0.f, 0.f};
  #pragma unroll
  for (int jt = 0; jt < 4; ++jt)
    #pragma unroll
    for (int d = 0; d < 2; ++d)
      #pragma unroll
      for (int qt = 0; qt < 4; ++qt)
        ot[d][qt] = __builtin_amdgcn_mfma_f32_16x16x16f16(Vh[jt][d], pf[jt][qt], ot[d][qt], 0, 0, 0);

  // ---- normalize, bounce O^T -> row-major per-wave LDS, coalesced copy-out ----
  h16* Ob = (h16*)(ldsbuf + wave * 5120);  // [64][40] (rows 16B-aligned); aliases staging (dead)
  #pragma unroll
  for (int d = 0; d < 2; ++d)
    #pragma unroll
    for (int qt = 0; qt < 4; ++qt) {
      h16x4 ov;
      #pragma unroll
      for (int r = 0; r < 4; ++r) ov[r] = (h16)(ot[d][qt][r] * rinv[qt]);
      *(h16x4*)(Ob + (16 * qt + l15) * 40 + 16 * d + 4 * lg) = ov;
    }
  __syncthreads();
  if (lane < 49) {
    h16* gdst = O + (rowbase + lane) * 512 + head * 32;
    #pragma unroll
    for (int c = 0; c < 4; ++c)
      *(h16x8*)(gdst + c * 8) = *(const h16x8*)(Ob + lane * 40 + c * 8);
  }
}

// ---------------- output projection: out = O @ w2 + proj_b ----------------
__global__ __launch_bounds__(256) void wa_proj(
    const h16* __restrict__ O, const h16* __restrict__ w2,
    const float* __restrict__ proj_b, float* __restrict__ out) {
  __shared__ __align__(16) h16 Alds[128][40];
  __shared__ __align__(16) h16 Blds[32][144];
  const int tid = threadIdx.x;
  const int wave = tid >> 6, lane = tid & 63;
  const int l15 = lane & 15, lg = lane >> 4;
  const int rowt = blockIdx.x >> 2, colt = blockIdx.x & 3;
  const int wr = wave >> 1, wc = wave & 1;

  f32x4 acc[4][4];
  #pragma unroll
  for (int a = 0; a < 4; ++a)
    #pragma unroll
    for (int b = 0; b < 4; ++b) acc[a][b] = (f32x4){0.f, 0.f, 0.f, 0.f};

  for (int kt = 0; kt < 16; ++kt) {
    #pragma unroll
    for (int p = 0; p < 2; ++p) {         // stage A 128x32
      int idx = tid + p * 256;
      int r = idx >> 2, c8 = (idx & 3) << 3;
      *(h16x8*)(&Alds[r][c8]) =
          *(const h16x8*)(O + (size_t)(rowt * 128 + r) * 512 + kt * 32 + c8);
    }
    #pragma unroll
    for (int p = 0; p < 2; ++p) {         // stage B 32x128
      int idx = tid + p * 256;
      int r = idx >> 4, c8 = (idx & 15) << 3;
      *(h16x8*)(&Blds[r][c8]) =
          *(const h16x8*)(w2 + (size_t)(kt * 32 + r) * 512 + colt * 128 + c8);
    }
    __syncthreads();
    #pragma unroll
    for (int ks = 0; ks < 2; ++ks) {
      h16x4 af[4], bf[4];
      #pragma unroll
      for (int mt = 0; mt < 4; ++mt)
        af[mt] = *(const h16x4*)(&Alds[wr * 64 + mt * 16 + l15][ks * 16 + lg * 4]);
      #pragma unroll
      for (int nt = 0; nt < 4; ++nt) {
        int col = wc * 64 + nt * 16 + l15;
        int kb = ks * 16 + lg * 4;
        bf[nt] = (h16x4){ Blds[kb][col], Blds[kb + 1][col], Blds[kb + 2][col], Blds[kb + 3][col] };
      }
      #pragma unroll
      for (int mt = 0; mt < 4; ++mt)
        #pragma unroll
        for (int nt = 0; nt < 4; ++nt)
          acc[mt][nt] = __builtin_amdgcn_mfma_f32_16x16x16f16(af[mt], bf[nt], acc[mt][nt], 0, 0, 0);
    }
    __syncthreads();
  }
  #pragma unroll
  for (int nt = 0; nt < 4; ++nt) {
    int col = colt * 128 + wc * 64 + nt * 16 + l15;
    float pb = proj_b[col];
    #pragma unroll
    for (int mt = 0; mt < 4; ++mt) {
      int row = rowt * 128 + wr * 64 + mt * 16 + 4 * lg;
      #pragma unroll
      for (int r = 0; r < 4; ++r)
        out[(size_t)(row + r) * 512 + col] = acc[mt][nt][r] + pb;
    }
  }
}

extern "C" void kernel_launch(void* const* d_in, const int* in_sizes, int n_in,
                              void* d_out, int out_size, void* d_ws, size_t ws_size,
                              hipStream_t stream) {
  const float* x          = (const float*)d_in[0];
  const float* qkv_w      = (const float*)d_in[1];
  const float* qkv_b      = (const float*)d_in[2];
  const float* proj_w     = (const float*)d_in[3];
  const float* proj_b     = (const float*)d_in[4];
  const float* bias_table = (const float*)d_in[5];
  float* out = (float*)d_out;

  char* ws = (char*)d_ws;
  h16*   O     = (h16*)ws;
  h16*   w1T   = (h16*)(ws + W1T_OFF);
  h16*   w2    = (h16*)(ws + W2_OFF);
  float* biasT = (float*)(ws + BT_OFF);
  h16*   x16   = (h16*)d_out;  // d_out is dead until wa_proj overwrites it

  wa_convert_x<<<50176, 256, 0, stream>>>(x, x16);
  wa_convert_pw<<<256, 256, 0, stream>>>(proj_w, w2);
  wa_transpose_w1<<<768, 256, 0, stream>>>(qkv_w, w1T);
  wa_build_bias<<<256, 256, 0, stream>>>(bias_table, biasT);
  wa_qkv_attn<<<4096 * 4, 256, 0, stream>>>(x16, qkv_b, w1T, biasT, O);
  wa_proj<<<1568 * 4, 256, 0, stream>>>(O, w2, proj_b, out);
}